// Round 1
// baseline (945.060 us; speedup 1.0000x reference)
//
#include <hip/hip_runtime.h>
#include <stdint.h>

// BitNet b1.58 column-parallel linear:
//   y[m,n] = (sum_k qx[m,k]*qw[n,k]) * inv_sx[m] * inv_sw + bias[n]
// M=8192 (B*S), N=16384 (D_OUT), K=4096 (D_IN)

#define M_ROWS 8192
#define N_COLS 16384
#define K_DIM  4096

typedef int v4i __attribute__((ext_vector_type(4)));

// ---------------- workspace layout ----------------
// [0,      8192)  : float partials[2048]
// [8192,   8200)  : float params[2] = {scale_w, inv_sw}
// [8448,  41216)  : float inv_sx[8192]
// [41216, +32MB)  : int8 qx[8192][4096]
// [then,  +64MB)  : int8 qw[16384][4096]
#define WS_PARTIALS 0
#define WS_PARAMS   8192
#define WS_INVSX    8448
#define WS_QX       41216
#define WS_QW       (41216 + 33554432)
#define WS_NEED     ((size_t)WS_QW + 67108864)

// ---------------- activation quant: per-row int8 absmax ----------------
__device__ __forceinline__ int quant_act1(float v, float s) {
    float q = rintf(v * s);               // round-half-even, matches jnp.round
    q = fminf(127.0f, fmaxf(-128.0f, q));
    return (int)q;
}

__global__ __launch_bounds__(256) void act_quant_kernel(const float* __restrict__ x,
                                                        int8_t* __restrict__ qx,
                                                        float* __restrict__ inv_sx) {
    const int row = blockIdx.x;
    const int t = threadIdx.x;
    const float4* xr = (const float4*)(x + (size_t)row * K_DIM);

    float4 v[4];
    float m = 0.0f;
#pragma unroll
    for (int i = 0; i < 4; ++i) {
        v[i] = xr[t + 256 * i];
        m = fmaxf(m, fmaxf(fmaxf(fabsf(v[i].x), fabsf(v[i].y)),
                           fmaxf(fabsf(v[i].z), fabsf(v[i].w))));
    }
#pragma unroll
    for (int off = 32; off > 0; off >>= 1) m = fmaxf(m, __shfl_xor(m, off));
    __shared__ float wm[4];
    if ((t & 63) == 0) wm[t >> 6] = m;
    __syncthreads();
    m = fmaxf(fmaxf(wm[0], wm[1]), fmaxf(wm[2], wm[3]));
    m = fmaxf(m, 1e-5f);                  // clip(max, EPS)
    const float scale = 127.0f / m;
    if (t == 0) inv_sx[row] = 1.0f / scale;

    int* qr = (int*)(qx + (size_t)row * K_DIM);
#pragma unroll
    for (int i = 0; i < 4; ++i) {
        int b0 = quant_act1(v[i].x, scale) & 255;
        int b1 = quant_act1(v[i].y, scale) & 255;
        int b2 = quant_act1(v[i].z, scale) & 255;
        int b3 = quant_act1(v[i].w, scale) & 255;
        qr[t + 256 * i] = b0 | (b1 << 8) | (b2 << 16) | (b3 << 24);
    }
}

// ---------------- weight abs-sum (deterministic two-stage) ----------------
__global__ __launch_bounds__(256) void wabs_partial_kernel(const float* __restrict__ w,
                                                           float* __restrict__ partials) {
    const int t = threadIdx.x;
    const size_t base = (size_t)blockIdx.x * 8192;   // float4 units, 32768 floats/block
    const float4* w4 = (const float4*)w;
    float s = 0.0f;
#pragma unroll 8
    for (int i = 0; i < 32; ++i) {
        float4 v = w4[base + (size_t)i * 256 + t];
        s += fabsf(v.x) + fabsf(v.y) + fabsf(v.z) + fabsf(v.w);
    }
#pragma unroll
    for (int off = 32; off > 0; off >>= 1) s += __shfl_xor(s, off);
    __shared__ float wp[4];
    if ((t & 63) == 0) wp[t >> 6] = s;
    __syncthreads();
    if (t == 0) partials[blockIdx.x] = (wp[0] + wp[1]) + (wp[2] + wp[3]);
}

__global__ __launch_bounds__(256) void wfinal_kernel(const float* __restrict__ partials,
                                                     float* __restrict__ params) {
    __shared__ double sh[256];
    const int t = threadIdx.x;
    double s = 0.0;
    for (int i = t; i < 2048; i += 256) s += (double)partials[i];
    sh[t] = s;
    __syncthreads();
    for (int off = 128; off > 0; off >>= 1) {
        if (t < off) sh[t] += sh[t + off];
        __syncthreads();
    }
    if (t == 0) {
        float mean = (float)(sh[0] / 67108864.0);
        mean = fmaxf(mean, 1e-5f);        // clip(mean, EPS)
        float scale = 1.0f / mean;        // scale_w
        params[0] = scale;
        params[1] = 1.0f / scale;         // inv_sw (matches ref's divide-by-scale)
    }
}

// ---------------- weight quant: per-tensor ternary ----------------
__device__ __forceinline__ int quant_w1(float v, float s) {
    float q = rintf(v * s);
    q = fminf(1.0f, fmaxf(-1.0f, q));
    return (int)q;
}

__global__ __launch_bounds__(256) void w_quant_kernel(const float* __restrict__ w,
                                                      int8_t* __restrict__ qw,
                                                      const float* __restrict__ params) {
    const float scale = params[0];
    const int stride = gridDim.x * 256;
    const float4* w4 = (const float4*)w;
    int* q4 = (int*)qw;
    for (int g = blockIdx.x * 256 + threadIdx.x; g < 16777216; g += stride) {
        float4 v = w4[g];
        int b0 = quant_w1(v.x, scale) & 255;
        int b1 = quant_w1(v.y, scale) & 255;
        int b2 = quant_w1(v.z, scale) & 255;
        int b3 = quant_w1(v.w, scale) & 255;
        q4[g] = b0 | (b1 << 8) | (b2 << 16) | (b3 << 24);
    }
}

// ---------------- int8 GEMM: 128x128 tile, BK=64, mfma_i32_16x16x64_i8 ----------------
// LDS tiles [128 rows][64 bytes], 16B-chunk XOR swizzle: slot = ksub ^ ((row>>1)&3).
// Swizzle applied on the GLOBAL source during global_load_lds staging (LDS stays
// linear) and on the ds_read address — both-sides involution (rule 21).
__global__ __launch_bounds__(256) void gemm_i8_kernel(const int8_t* __restrict__ qx,
                                                      const int8_t* __restrict__ qw,
                                                      const float* __restrict__ inv_sx,
                                                      const float* __restrict__ params,
                                                      const float* __restrict__ bias,
                                                      float* __restrict__ y) {
    __shared__ __align__(16) int8_t As[2][128 * 64];
    __shared__ __align__(16) int8_t Bs[2][128 * 64];

    const int t = threadIdx.x;
    const int lane = t & 63;
    const int w = t >> 6;

    // XCD-aware bijective swizzle: 8192 blocks, 8 XCDs
    const int bid = blockIdx.x;
    const int swz = (bid & 7) * 1024 + (bid >> 3);
    const int bn = swz & 127;   // 128 n-blocks (fast: consecutive share A-tile)
    const int bm = swz >> 7;    // 64 m-blocks

    const size_t arow0 = (size_t)bm * 128;
    const size_t brow0 = (size_t)bn * 128;

    // staging: 512 16B-chunks per tile; thread t handles chunks t and 256+t
    const int c0 = t, c1 = 256 + t;
    const int r0 = c0 >> 2, s0 = c0 & 3;
    const int r1 = c1 >> 2, s1 = c1 & 3;
    const int k0 = s0 ^ ((r0 >> 1) & 3);
    const int k1 = s1 ^ ((r1 >> 1) & 3);
    const int8_t* ga0 = qx + (arow0 + r0) * K_DIM + k0 * 16;
    const int8_t* ga1 = qx + (arow0 + r1) * K_DIM + k1 * 16;
    const int8_t* gb0 = qw + (brow0 + r0) * K_DIM + k0 * 16;
    const int8_t* gb1 = qw + (brow0 + r1) * K_DIM + k1 * 16;

#define STAGE(buf, kt)                                                                             \
    do {                                                                                           \
        __builtin_amdgcn_global_load_lds(                                                          \
            (const __attribute__((address_space(1))) void*)(ga0 + (kt)),                           \
            (__attribute__((address_space(3))) void*)&As[buf][(w * 64) * 16], 16, 0, 0);           \
        __builtin_amdgcn_global_load_lds(                                                          \
            (const __attribute__((address_space(1))) void*)(ga1 + (kt)),                           \
            (__attribute__((address_space(3))) void*)&As[buf][(256 + w * 64) * 16], 16, 0, 0);     \
        __builtin_amdgcn_global_load_lds(                                                          \
            (const __attribute__((address_space(1))) void*)(gb0 + (kt)),                           \
            (__attribute__((address_space(3))) void*)&Bs[buf][(w * 64) * 16], 16, 0, 0);           \
        __builtin_amdgcn_global_load_lds(                                                          \
            (const __attribute__((address_space(1))) void*)(gb1 + (kt)),                           \
            (__attribute__((address_space(3))) void*)&Bs[buf][(256 + w * 64) * 16], 16, 0, 0);     \
    } while (0)

    // wave -> 64x64 output sub-tile
    const int wr = w >> 1, wc = w & 1;
    const int ksub = lane >> 4;          // k-chunk 0..3 (16 bytes each)
    const int lrow = lane & 15;

    int aoff[4], boff[4];
#pragma unroll
    for (int i = 0; i < 4; ++i) {
        int ra = wr * 64 + i * 16 + lrow;
        aoff[i] = ra * 64 + ((ksub ^ ((ra >> 1) & 3)) << 4);
        int rb = wc * 64 + i * 16 + lrow;
        boff[i] = rb * 64 + ((ksub ^ ((rb >> 1) & 3)) << 4);
    }

    v4i acc[4][4];
#pragma unroll
    for (int i = 0; i < 4; ++i)
#pragma unroll
        for (int j = 0; j < 4; ++j) acc[i][j] = (v4i){0, 0, 0, 0};

#define COMPUTE(buf)                                                                   \
    do {                                                                               \
        v4i a[4], b[4];                                                                \
        _Pragma("unroll") for (int i = 0; i < 4; ++i)                                  \
            a[i] = *(const v4i*)&As[buf][aoff[i]];                                     \
        _Pragma("unroll") for (int i = 0; i < 4; ++i)                                  \
            b[i] = *(const v4i*)&Bs[buf][boff[i]];                                     \
        _Pragma("unroll") for (int i = 0; i < 4; ++i)                                  \
            _Pragma("unroll") for (int j = 0; j < 4; ++j)                              \
                acc[i][j] = __builtin_amdgcn_mfma_i32_16x16x64_i8(a[i], b[j],          \
                                                                  acc[i][j], 0, 0, 0); \
    } while (0)

    STAGE(0, 0);
    __syncthreads();    // includes vmcnt(0) drain
    int cur = 0;
#pragma unroll 1
    for (int kt = 64; kt < K_DIM; kt += 64) {
        STAGE(cur ^ 1, kt);
        COMPUTE(cur);
        __syncthreads();
        cur ^= 1;
    }
    COMPUTE(cur);

    // epilogue: y = acc * inv_sx[row] * inv_sw + bias[col]
    const float invsw = params[1];
    const int rl = (lane >> 4) * 4;
#pragma unroll
    for (int i = 0; i < 4; ++i) {
        const int grow_base = (int)arow0 + wr * 64 + i * 16 + rl;
        float isx[4];
#pragma unroll
        for (int r = 0; r < 4; ++r) isx[r] = inv_sx[grow_base + r] * invsw;
#pragma unroll
        for (int j = 0; j < 4; ++j) {
            const int gcol = (int)brow0 + wc * 64 + j * 16 + lrow;
            const float bb = bias[gcol];
#pragma unroll
            for (int r = 0; r < 4; ++r) {
                y[(size_t)(grow_base + r) * N_COLS + gcol] =
                    (float)acc[i][j][r] * isx[r] + bb;
            }
        }
    }
#undef STAGE
#undef COMPUTE
}

// ---------------- launch ----------------
extern "C" void kernel_launch(void* const* d_in, const int* in_sizes, int n_in,
                              void* d_out, int out_size, void* d_ws, size_t ws_size,
                              hipStream_t stream) {
    const float* x    = (const float*)d_in[0];
    const float* wt   = (const float*)d_in[1];
    const float* bias = (const float*)d_in[2];
    float* y = (float*)d_out;

    if (ws_size < WS_NEED) return;   // workspace too small — bail safely

    char* ws = (char*)d_ws;
    float* partials = (float*)(ws + WS_PARTIALS);
    float* params   = (float*)(ws + WS_PARAMS);
    float* inv_sx   = (float*)(ws + WS_INVSX);
    int8_t* qx = (int8_t*)(ws + WS_QX);
    int8_t* qw = (int8_t*)(ws + WS_QW);

    hipLaunchKernelGGL(act_quant_kernel,   dim3(8192), dim3(256), 0, stream, x, qx, inv_sx);
    hipLaunchKernelGGL(wabs_partial_kernel,dim3(2048), dim3(256), 0, stream, wt, partials);
    hipLaunchKernelGGL(wfinal_kernel,      dim3(1),    dim3(256), 0, stream, partials, params);
    hipLaunchKernelGGL(w_quant_kernel,     dim3(4096), dim3(256), 0, stream, wt, qw, params);
    hipLaunchKernelGGL(gemm_i8_kernel,     dim3(8192), dim3(256), 0, stream,
                       qx, qw, inv_sx, params, bias, y);
}

// Round 2
// 904.268 us; speedup vs baseline: 1.0451x; 1.0451x over previous
//
#include <hip/hip_runtime.h>
#include <stdint.h>

// BitNet b1.58 column-parallel linear:
//   y[m,n] = (sum_k qx[m,k]*qw[n,k]) * inv_sx[m] * inv_sw + bias[n]
// M=8192 (B*S), N=16384 (D_OUT), K=4096 (D_IN)

#define M_ROWS 8192
#define N_COLS 16384
#define K_DIM  4096
#define NT     (K_DIM / 64)   // 64 K-tiles of 64 bytes

typedef int v4i __attribute__((ext_vector_type(4)));

// ---------------- workspace layout ----------------
#define WS_PARTIALS 0
#define WS_PARAMS   8192
#define WS_INVSX    8448
#define WS_QX       41216
#define WS_QW       (41216 + 33554432)
#define WS_NEED     ((size_t)WS_QW + 67108864)

// ---------------- activation quant: per-row int8 absmax ----------------
__device__ __forceinline__ int quant_act1(float v, float s) {
    float q = rintf(v * s);               // round-half-even, matches jnp.round
    q = fminf(127.0f, fmaxf(-128.0f, q));
    return (int)q;
}

__global__ __launch_bounds__(256) void act_quant_kernel(const float* __restrict__ x,
                                                        int8_t* __restrict__ qx,
                                                        float* __restrict__ inv_sx) {
    const int row = blockIdx.x;
    const int t = threadIdx.x;
    const float4* xr = (const float4*)(x + (size_t)row * K_DIM);

    float4 v[4];
    float m = 0.0f;
#pragma unroll
    for (int i = 0; i < 4; ++i) {
        v[i] = xr[t + 256 * i];
        m = fmaxf(m, fmaxf(fmaxf(fabsf(v[i].x), fabsf(v[i].y)),
                           fmaxf(fabsf(v[i].z), fabsf(v[i].w))));
    }
#pragma unroll
    for (int off = 32; off > 0; off >>= 1) m = fmaxf(m, __shfl_xor(m, off));
    __shared__ float wm[4];
    if ((t & 63) == 0) wm[t >> 6] = m;
    __syncthreads();
    m = fmaxf(fmaxf(wm[0], wm[1]), fmaxf(wm[2], wm[3]));
    m = fmaxf(m, 1e-5f);                  // clip(max, EPS)
    const float scale = 127.0f / m;
    if (t == 0) inv_sx[row] = 1.0f / scale;

    int* qr = (int*)(qx + (size_t)row * K_DIM);
#pragma unroll
    for (int i = 0; i < 4; ++i) {
        int b0 = quant_act1(v[i].x, scale) & 255;
        int b1 = quant_act1(v[i].y, scale) & 255;
        int b2 = quant_act1(v[i].z, scale) & 255;
        int b3 = quant_act1(v[i].w, scale) & 255;
        qr[t + 256 * i] = b0 | (b1 << 8) | (b2 << 16) | (b3 << 24);
    }
}

// ---------------- weight abs-sum (deterministic two-stage) ----------------
__global__ __launch_bounds__(256) void wabs_partial_kernel(const float* __restrict__ w,
                                                           float* __restrict__ partials) {
    const int t = threadIdx.x;
    const size_t base = (size_t)blockIdx.x * 8192;   // float4 units
    const float4* w4 = (const float4*)w;
    float s = 0.0f;
#pragma unroll 8
    for (int i = 0; i < 32; ++i) {
        float4 v = w4[base + (size_t)i * 256 + t];
        s += fabsf(v.x) + fabsf(v.y) + fabsf(v.z) + fabsf(v.w);
    }
#pragma unroll
    for (int off = 32; off > 0; off >>= 1) s += __shfl_xor(s, off);
    __shared__ float wp[4];
    if ((t & 63) == 0) wp[t >> 6] = s;
    __syncthreads();
    if (t == 0) partials[blockIdx.x] = (wp[0] + wp[1]) + (wp[2] + wp[3]);
}

__global__ __launch_bounds__(256) void wfinal_kernel(const float* __restrict__ partials,
                                                     float* __restrict__ params) {
    __shared__ double sh[256];
    const int t = threadIdx.x;
    double s = 0.0;
    for (int i = t; i < 2048; i += 256) s += (double)partials[i];
    sh[t] = s;
    __syncthreads();
    for (int off = 128; off > 0; off >>= 1) {
        if (t < off) sh[t] += sh[t + off];
        __syncthreads();
    }
    if (t == 0) {
        float mean = (float)(sh[0] / 67108864.0);
        mean = fmaxf(mean, 1e-5f);        // clip(mean, EPS)
        float scale = 1.0f / mean;        // scale_w
        params[0] = scale;
        params[1] = 1.0f / scale;         // inv_sw
    }
}

// ---------------- weight quant: per-tensor ternary ----------------
__device__ __forceinline__ int quant_w1(float v, float s) {
    float q = rintf(v * s);
    q = fminf(1.0f, fmaxf(-1.0f, q));
    return (int)q;
}

__global__ __launch_bounds__(256) void w_quant_kernel(const float* __restrict__ w,
                                                      int8_t* __restrict__ qw,
                                                      const float* __restrict__ params) {
    const float scale = params[0];
    const int stride = gridDim.x * 256;
    const float4* w4 = (const float4*)w;
    int* q4 = (int*)qw;
    for (int g = blockIdx.x * 256 + threadIdx.x; g < 16777216; g += stride) {
        float4 v = w4[g];
        int b0 = quant_w1(v.x, scale) & 255;
        int b1 = quant_w1(v.y, scale) & 255;
        int b2 = quant_w1(v.z, scale) & 255;
        int b3 = quant_w1(v.w, scale) & 255;
        q4[g] = b0 | (b1 << 8) | (b2 << 16) | (b3 << 24);
    }
}

// ---------------- int8 GEMM: 256x256 tile, BK=64B, 4-deep LDS ring, counted vmcnt --------
// 8 waves (2M x 4N), per-wave 128x64 output, mfma_i32_16x16x64_i8.
// LDS: As[4][256][64], Bs[4][256][64] = 128 KB. Compute tile t, tiles t+1..t+3 in flight.
// vmcnt(8) at iteration top = tiles t+1,t+2 (4 loads each) may be outstanding => tile t landed.
// Raw s_barrier (NOT __syncthreads, which would drain vmcnt(0)).
// 16B-chunk XOR swizzle (slot ^= (row>>1)&3) applied on global SOURCE during staging and on
// ds_read address — both-sides involution (verified round 1: 0 bank conflicts, absmax ok).
__global__ __launch_bounds__(512, 2) void gemm_i8_kernel(const int8_t* __restrict__ qx,
                                                         const int8_t* __restrict__ qw,
                                                         const float* __restrict__ inv_sx,
                                                         const float* __restrict__ params,
                                                         const float* __restrict__ bias,
                                                         float* __restrict__ y) {
    __shared__ __align__(16) int8_t As[4][16384];
    __shared__ __align__(16) int8_t Bs[4][16384];
    int8_t* AsB = &As[0][0];
    int8_t* BsB = &Bs[0][0];

    const int tid = threadIdx.x;
    const int lane = tid & 63;
    const int w = tid >> 6;           // wave 0..7
    const int wr = w >> 2;            // 0..1  (M half)
    const int wc = w & 3;             // 0..3  (N quarter)
    const int wbase = w * 1024;       // wave-uniform LDS staging base (64 lanes x 16B)

    // XCD-aware bijective swizzle: 2048 blocks, 8 XCDs (2048 % 8 == 0)
    const int bid = blockIdx.x;
    const int swz = (bid & 7) * 256 + (bid >> 3);
    const int bn = swz & 63;          // 64 n-blocks (fast within XCD: share A-panel)
    const int bm = swz >> 6;          // 32 m-blocks

    const size_t arow0 = (size_t)bm * 256;
    const size_t brow0 = (size_t)bn * 256;

    // staging addressing: 512 chunks of 16B per 128-row half; thread tid -> chunk tid
    const int r0 = tid >> 2;                       // row 0..127 within half
    const int kc0 = (tid & 3) ^ ((r0 >> 1) & 3);   // swizzled k-slot (inverse == forward)
    const int8_t* gA0 = qx + (arow0 + r0) * K_DIM + kc0 * 16;
    const int8_t* gA1 = gA0 + (size_t)128 * K_DIM;
    const int8_t* gB0 = qw + (brow0 + r0) * K_DIM + kc0 * 16;
    const int8_t* gB1 = gB0 + (size_t)128 * K_DIM;

#define ISSUE(tt)                                                                                  \
    do {                                                                                           \
        const int _buf = (tt) & 3;                                                                 \
        const size_t _ko = (size_t)(tt) * 64;                                                      \
        __builtin_amdgcn_global_load_lds(                                                          \
            (const __attribute__((address_space(1))) void*)(gA0 + _ko),                            \
            (__attribute__((address_space(3))) void*)(AsB + _buf * 16384 + wbase), 16, 0, 0);      \
        __builtin_amdgcn_global_load_lds(                                                          \
            (const __attribute__((address_space(1))) void*)(gA1 + _ko),                            \
            (__attribute__((address_space(3))) void*)(AsB + _buf * 16384 + 8192 + wbase), 16, 0,   \
            0);                                                                                    \
        __builtin_amdgcn_global_load_lds(                                                          \
            (const __attribute__((address_space(1))) void*)(gB0 + _ko),                            \
            (__attribute__((address_space(3))) void*)(BsB + _buf * 16384 + wbase), 16, 0, 0);      \
        __builtin_amdgcn_global_load_lds(                                                          \
            (const __attribute__((address_space(1))) void*)(gB1 + _ko),                            \
            (__attribute__((address_space(3))) void*)(BsB + _buf * 16384 + 8192 + wbase), 16, 0,   \
            0);                                                                                    \
    } while (0)

    // fragment ds_read offsets (within one tile buffer)
    const int ksub = lane >> 4;       // 16B k-chunk 0..3
    const int lrow = lane & 15;
    int aoff[8], boff[4];
#pragma unroll
    for (int i = 0; i < 8; ++i) {
        int ra = wr * 128 + i * 16 + lrow;
        aoff[i] = ra * 64 + ((ksub ^ ((ra >> 1) & 3)) << 4);
    }
#pragma unroll
    for (int j = 0; j < 4; ++j) {
        int rb = wc * 64 + j * 16 + lrow;
        boff[j] = rb * 64 + ((ksub ^ ((rb >> 1) & 3)) << 4);
    }

    v4i acc[8][4];
#pragma unroll
    for (int i = 0; i < 8; ++i)
#pragma unroll
        for (int j = 0; j < 4; ++j) acc[i][j] = (v4i){0, 0, 0, 0};

#define COMPUTE(tt)                                                                    \
    do {                                                                               \
        const int8_t* _pa = AsB + ((tt) & 3) * 16384;                                  \
        const int8_t* _pb = BsB + ((tt) & 3) * 16384;                                  \
        v4i _a[8], _b[4];                                                              \
        _Pragma("unroll") for (int i = 0; i < 8; ++i)                                  \
            _a[i] = *(const v4i*)(_pa + aoff[i]);                                      \
        _Pragma("unroll") for (int j = 0; j < 4; ++j)                                  \
            _b[j] = *(const v4i*)(_pb + boff[j]);                                      \
        __builtin_amdgcn_s_setprio(1);                                                 \
        _Pragma("unroll") for (int i = 0; i < 8; ++i)                                  \
            _Pragma("unroll") for (int j = 0; j < 4; ++j)                              \
                acc[i][j] = __builtin_amdgcn_mfma_i32_16x16x64_i8(_a[i], _b[j],        \
                                                                  acc[i][j], 0, 0, 0); \
        __builtin_amdgcn_s_setprio(0);                                                 \
    } while (0)

    // prologue: fill pipeline with tiles 0,1,2 (12 loads in flight)
    ISSUE(0);
    ISSUE(1);
    ISSUE(2);

#pragma unroll 1
    for (int t = 0; t < NT - 3; ++t) {
        __builtin_amdgcn_sched_barrier(0);
        asm volatile("s_waitcnt vmcnt(8)" ::: "memory");   // tile t landed (t+1,t+2 in flight)
        __builtin_amdgcn_s_barrier();                      // publish across waves
        __builtin_amdgcn_sched_barrier(0);
        ISSUE(t + 3);                                      // overwrite buf (t-1)&3 — safe post-barrier
        COMPUTE(t);
    }
    // epilogue: drain remaining 3 tiles
    __builtin_amdgcn_sched_barrier(0);
    asm volatile("s_waitcnt vmcnt(0)" ::: "memory");
    __builtin_amdgcn_s_barrier();
    __builtin_amdgcn_sched_barrier(0);
    COMPUTE(NT - 3);
    COMPUTE(NT - 2);
    COMPUTE(NT - 1);

    // epilogue: y = acc * inv_sx[row] * inv_sw + bias[col]
    const float invsw = params[1];
    const int rl = (lane >> 4) * 4;
#pragma unroll
    for (int i = 0; i < 8; ++i) {
        const int grow_base = (int)arow0 + wr * 128 + i * 16 + rl;
        float isx[4];
#pragma unroll
        for (int r = 0; r < 4; ++r) isx[r] = inv_sx[grow_base + r] * invsw;
#pragma unroll
        for (int j = 0; j < 4; ++j) {
            const int gcol = (int)brow0 + wc * 64 + j * 16 + lrow;
            const float bb = bias[gcol];
#pragma unroll
            for (int r = 0; r < 4; ++r) {
                y[(size_t)(grow_base + r) * N_COLS + gcol] =
                    (float)acc[i][j][r] * isx[r] + bb;
            }
        }
    }
#undef ISSUE
#undef COMPUTE
}

// ---------------- launch ----------------
extern "C" void kernel_launch(void* const* d_in, const int* in_sizes, int n_in,
                              void* d_out, int out_size, void* d_ws, size_t ws_size,
                              hipStream_t stream) {
    const float* x    = (const float*)d_in[0];
    const float* wt   = (const float*)d_in[1];
    const float* bias = (const float*)d_in[2];
    float* y = (float*)d_out;

    if (ws_size < WS_NEED) return;

    char* ws = (char*)d_ws;
    float* partials = (float*)(ws + WS_PARTIALS);
    float* params   = (float*)(ws + WS_PARAMS);
    float* inv_sx   = (float*)(ws + WS_INVSX);
    int8_t* qx = (int8_t*)(ws + WS_QX);
    int8_t* qw = (int8_t*)(ws + WS_QW);

    hipLaunchKernelGGL(act_quant_kernel,   dim3(8192), dim3(256), 0, stream, x, qx, inv_sx);
    hipLaunchKernelGGL(wabs_partial_kernel,dim3(2048), dim3(256), 0, stream, wt, partials);
    hipLaunchKernelGGL(wfinal_kernel,      dim3(1),    dim3(256), 0, stream, partials, params);
    hipLaunchKernelGGL(w_quant_kernel,     dim3(4096), dim3(256), 0, stream, wt, qw, params);
    hipLaunchKernelGGL(gemm_i8_kernel,     dim3(2048), dim3(512), 0, stream,
                       qx, qw, inv_sx, params, bias, y);
}

// Round 3
// 808.939 us; speedup vs baseline: 1.1683x; 1.1178x over previous
//
#include <hip/hip_runtime.h>
#include <stdint.h>

// BitNet b1.58 column-parallel linear:
//   y[m,n] = (sum_k qx[m,k]*qw[n,k]) * inv_sx[m] * inv_sw + bias[n]
// M=8192 (B*S), N=16384 (D_OUT), K=4096 (D_IN)

#define M_ROWS 8192
#define N_COLS 16384
#define K_DIM  4096
#define NT     (K_DIM / 64)   // 64 K-steps of 64 bytes

typedef int v4i __attribute__((ext_vector_type(4)));

// ---------------- workspace layout ----------------
#define WS_PARTIALS 0
#define WS_PARAMS   8192
#define WS_INVSX    8448
#define WS_QX       41216
#define WS_QW       (41216 + 33554432)
#define WS_NEED     ((size_t)WS_QW + 67108864)

// ---------------- activation quant: per-row int8 absmax ----------------
__device__ __forceinline__ int quant_act1(float v, float s) {
    float q = rintf(v * s);               // round-half-even, matches jnp.round
    q = fminf(127.0f, fmaxf(-128.0f, q));
    return (int)q;
}

__global__ __launch_bounds__(256) void act_quant_kernel(const float* __restrict__ x,
                                                        int8_t* __restrict__ qx,
                                                        float* __restrict__ inv_sx) {
    const int row = blockIdx.x;
    const int t = threadIdx.x;
    const float4* xr = (const float4*)(x + (size_t)row * K_DIM);

    float4 v[4];
    float m = 0.0f;
#pragma unroll
    for (int i = 0; i < 4; ++i) {
        v[i] = xr[t + 256 * i];
        m = fmaxf(m, fmaxf(fmaxf(fabsf(v[i].x), fabsf(v[i].y)),
                           fmaxf(fabsf(v[i].z), fabsf(v[i].w))));
    }
#pragma unroll
    for (int off = 32; off > 0; off >>= 1) m = fmaxf(m, __shfl_xor(m, off));
    __shared__ float wm[4];
    if ((t & 63) == 0) wm[t >> 6] = m;
    __syncthreads();
    m = fmaxf(fmaxf(wm[0], wm[1]), fmaxf(wm[2], wm[3]));
    m = fmaxf(m, 1e-5f);                  // clip(max, EPS)
    const float scale = 127.0f / m;
    if (t == 0) inv_sx[row] = 1.0f / scale;

    int* qr = (int*)(qx + (size_t)row * K_DIM);
#pragma unroll
    for (int i = 0; i < 4; ++i) {
        int b0 = quant_act1(v[i].x, scale) & 255;
        int b1 = quant_act1(v[i].y, scale) & 255;
        int b2 = quant_act1(v[i].z, scale) & 255;
        int b3 = quant_act1(v[i].w, scale) & 255;
        qr[t + 256 * i] = b0 | (b1 << 8) | (b2 << 16) | (b3 << 24);
    }
}

// ---------------- weight abs-sum (deterministic two-stage) ----------------
__global__ __launch_bounds__(256) void wabs_partial_kernel(const float* __restrict__ w,
                                                           float* __restrict__ partials) {
    const int t = threadIdx.x;
    const size_t base = (size_t)blockIdx.x * 8192;   // float4 units
    const float4* w4 = (const float4*)w;
    float s = 0.0f;
#pragma unroll 8
    for (int i = 0; i < 32; ++i) {
        float4 v = w4[base + (size_t)i * 256 + t];
        s += fabsf(v.x) + fabsf(v.y) + fabsf(v.z) + fabsf(v.w);
    }
#pragma unroll
    for (int off = 32; off > 0; off >>= 1) s += __shfl_xor(s, off);
    __shared__ float wp[4];
    if ((t & 63) == 0) wp[t >> 6] = s;
    __syncthreads();
    if (t == 0) partials[blockIdx.x] = (wp[0] + wp[1]) + (wp[2] + wp[3]);
}

__global__ __launch_bounds__(256) void wfinal_kernel(const float* __restrict__ partials,
                                                     float* __restrict__ params) {
    __shared__ double sh[256];
    const int t = threadIdx.x;
    double s = 0.0;
    for (int i = t; i < 2048; i += 256) s += (double)partials[i];
    sh[t] = s;
    __syncthreads();
    for (int off = 128; off > 0; off >>= 1) {
        if (t < off) sh[t] += sh[t + off];
        __syncthreads();
    }
    if (t == 0) {
        float mean = (float)(sh[0] / 67108864.0);
        mean = fmaxf(mean, 1e-5f);        // clip(mean, EPS)
        float scale = 1.0f / mean;        // scale_w
        params[0] = scale;
        params[1] = 1.0f / scale;         // inv_sw
    }
}

// ---------------- weight quant: per-tensor ternary ----------------
__device__ __forceinline__ int quant_w1(float v, float s) {
    float q = rintf(v * s);
    q = fminf(1.0f, fmaxf(-1.0f, q));
    return (int)q;
}

__global__ __launch_bounds__(256) void w_quant_kernel(const float* __restrict__ w,
                                                      int8_t* __restrict__ qw,
                                                      const float* __restrict__ params) {
    const float scale = params[0];
    const int stride = gridDim.x * 256;
    const float4* w4 = (const float4*)w;
    int* q4 = (int*)qw;
    for (int g = blockIdx.x * 256 + threadIdx.x; g < 16777216; g += stride) {
        float4 v = w4[g];
        int b0 = quant_w1(v.x, scale) & 255;
        int b1 = quant_w1(v.y, scale) & 255;
        int b2 = quant_w1(v.z, scale) & 255;
        int b3 = quant_w1(v.w, scale) & 255;
        q4[g] = b0 | (b1 << 8) | (b2 << 16) | (b3 << 24);
    }
}

// ---------------- int8 GEMM: 256x256 tile, 8-phase schedule, 4-ring LDS, counted vmcnt ----
// 8 waves (2M x 4N), per-wave 128x64 output, mfma_i32_16x16x64_i8.
// Iter = 2 K-steps (64B each, slot = ks&3). Each K-step = 4 phases:
//   { ds_read quadrant frags | issue 1 global_load_lds | s_barrier | lgkmcnt(0) |
//     setprio(1) 8xMFMA setprio(0) | s_barrier }
// vmcnt(4) only at phases 4 & 8 (newest 4 outstanding = next staged K-step's loads,
// proving the K-step about to be read has landed). Never vmcnt(0) in the main loop.
// 16B-chunk XOR swizzle on both global source and ds_read address (verified: 0 conflicts).
__global__ __launch_bounds__(512, 2) void gemm_i8_kernel(const int8_t* __restrict__ qx,
                                                         const int8_t* __restrict__ qw,
                                                         const float* __restrict__ inv_sx,
                                                         const float* __restrict__ params,
                                                         const float* __restrict__ bias,
                                                         float* __restrict__ y) {
    __shared__ __align__(16) int8_t As[4][16384];
    __shared__ __align__(16) int8_t Bs[4][16384];
    int8_t* AsB = &As[0][0];
    int8_t* BsB = &Bs[0][0];

    const int tid = threadIdx.x;
    const int lane = tid & 63;
    const int w = tid >> 6;           // wave 0..7
    const int wr = w >> 2;            // 0..1  (M half)
    const int wc = w & 3;             // 0..3  (N quarter)
    const int wbase = w * 1024;       // wave-uniform LDS staging base (64 lanes x 16B)

    // XCD-aware bijective swizzle: 2048 blocks, 8 XCDs
    const int bid = blockIdx.x;
    const int swz = (bid & 7) * 256 + (bid >> 3);
    const int bn = swz & 63;          // 64 n-blocks
    const int bm = swz >> 6;          // 32 m-blocks

    const size_t arow0 = (size_t)bm * 256;
    const size_t brow0 = (size_t)bn * 256;

    // staging addressing: 512 chunks of 16B per 128-row half; thread tid -> chunk tid
    const int r0 = tid >> 2;                       // row 0..127 within half
    const int kc0 = (tid & 3) ^ ((r0 >> 1) & 3);   // swizzled k-slot (involution)
    const int8_t* gA0 = qx + (arow0 + r0) * K_DIM + kc0 * 16;
    const int8_t* gA1 = gA0 + (size_t)128 * K_DIM;
    const int8_t* gB0 = qw + (brow0 + r0) * K_DIM + kc0 * 16;
    const int8_t* gB1 = gB0 + (size_t)128 * K_DIM;

#define GLD(g, l)                                                                      \
    __builtin_amdgcn_global_load_lds((const __attribute__((address_space(1))) void*)(g), \
                                     (__attribute__((address_space(3))) void*)(l), 16, 0, 0)

    // fragment ds_read offsets (within one 16KB slot)
    const int ksub = lane >> 4;       // 16B k-chunk 0..3
    const int lrow = lane & 15;
    int aoff[8], boff[4];
#pragma unroll
    for (int i = 0; i < 8; ++i) {
        int ra = wr * 128 + i * 16 + lrow;
        aoff[i] = ra * 64 + ((ksub ^ ((ra >> 1) & 3)) << 4);
    }
#pragma unroll
    for (int j = 0; j < 4; ++j) {
        int rb = wc * 64 + j * 16 + lrow;
        boff[j] = rb * 64 + ((ksub ^ ((rb >> 1) & 3)) << 4);
    }

    v4i acc[8][4];
#pragma unroll
    for (int i = 0; i < 8; ++i)
#pragma unroll
        for (int j = 0; j < 4; ++j) acc[i][j] = (v4i){0, 0, 0, 0};

    v4i a[8], b[4];

#define RDA4(base_, lo)                                                        \
    do {                                                                       \
        _Pragma("unroll") for (int _i = 0; _i < 4; ++_i)                       \
            a[(lo) + _i] = *(const v4i*)((base_) + aoff[(lo) + _i]);           \
    } while (0)
#define RDB2(base_, lo)                                                        \
    do {                                                                       \
        _Pragma("unroll") for (int _j = 0; _j < 2; ++_j)                       \
            b[(lo) + _j] = *(const v4i*)((base_) + boff[(lo) + _j]);           \
    } while (0)

#define MFMA8(mh, nh)                                                                       \
    do {                                                                                    \
        __builtin_amdgcn_s_setprio(1);                                                      \
        _Pragma("unroll") for (int _i = 0; _i < 4; ++_i)                                    \
            _Pragma("unroll") for (int _j = 0; _j < 2; ++_j)                                \
                acc[(mh) * 4 + _i][(nh) * 2 + _j] = __builtin_amdgcn_mfma_i32_16x16x64_i8(  \
                    a[(mh) * 4 + _i], b[(nh) * 2 + _j], acc[(mh) * 4 + _i][(nh) * 2 + _j],  \
                    0, 0, 0);                                                               \
        __builtin_amdgcn_s_setprio(0);                                                      \
    } while (0)

#define BARR()  __builtin_amdgcn_s_barrier()
#define LGKM0()                                                  \
    do {                                                         \
        asm volatile("s_waitcnt lgkmcnt(0)" ::: "memory");       \
        __builtin_amdgcn_sched_barrier(0);                       \
    } while (0)

// One K-step = 4 phases. pa_/pb_ = slot base pointers; fks = K-step to stage
// (ignored when STG==0); VMSTR = vmcnt immediate at phase 4 (stringized).
#define GROUP4(pa_, pb_, fks, STG, VMSTR)                                                   \
    do {                                                                                    \
        /* P0 */                                                                            \
        RDA4(pa_, 0);                                                                       \
        RDB2(pb_, 0);                                                                       \
        if (STG) GLD(gA0 + (size_t)(fks) * 64, AsB + ((fks) & 3) * 16384 + wbase);          \
        BARR();                                                                             \
        LGKM0();                                                                            \
        MFMA8(0, 0);                                                                        \
        BARR();                                                                             \
        /* P1 */                                                                            \
        RDB2(pb_, 2);                                                                       \
        if (STG) GLD(gA1 + (size_t)(fks) * 64, AsB + ((fks) & 3) * 16384 + 8192 + wbase);   \
        BARR();                                                                             \
        LGKM0();                                                                            \
        MFMA8(0, 1);                                                                        \
        BARR();                                                                             \
        /* P2 */                                                                            \
        RDA4(pa_, 4);                                                                       \
        if (STG) GLD(gB0 + (size_t)(fks) * 64, BsB + ((fks) & 3) * 16384 + wbase);          \
        BARR();                                                                             \
        LGKM0();                                                                            \
        MFMA8(1, 0);                                                                        \
        BARR();                                                                             \
        /* P3: counted vmcnt — publish next K-step's slot */                                \
        if (STG) GLD(gB1 + (size_t)(fks) * 64, BsB + ((fks) & 3) * 16384 + 8192 + wbase);   \
        asm volatile("s_waitcnt vmcnt(" VMSTR ")" ::: "memory");                            \
        BARR();                                                                             \
        __builtin_amdgcn_sched_barrier(0);                                                  \
        MFMA8(1, 1);                                                                        \
        BARR();                                                                             \
    } while (0)

    // prologue: stage K-steps 0 and 1 (8 loads/thread), confirm K-step 0 landed
    GLD(gA0, AsB + wbase);
    GLD(gA1, AsB + 8192 + wbase);
    GLD(gB0, BsB + wbase);
    GLD(gB1, BsB + 8192 + wbase);
    GLD(gA0 + 64, AsB + 16384 + wbase);
    GLD(gA1 + 64, AsB + 16384 + 8192 + wbase);
    GLD(gB0 + 64, BsB + 16384 + wbase);
    GLD(gB1 + 64, BsB + 16384 + 8192 + wbase);
    asm volatile("s_waitcnt vmcnt(4)" ::: "memory");
    BARR();

#pragma unroll 1
    for (int i = 0; i < 31; ++i) {
        const int t0 = 2 * i;
        const int8_t* pa0 = AsB + (t0 & 3) * 16384;
        const int8_t* pb0 = BsB + (t0 & 3) * 16384;
        const int8_t* pa1 = AsB + ((t0 + 1) & 3) * 16384;
        const int8_t* pb1 = BsB + ((t0 + 1) & 3) * 16384;
        GROUP4(pa0, pb0, t0 + 2, 1, "4");   // K-step 2i,   stage 2i+2
        GROUP4(pa1, pb1, t0 + 3, 1, "4");   // K-step 2i+1, stage 2i+3
    }
    // peeled final iter: K-steps 62 (slot 2) and 63 (slot 3), no staging
    GROUP4(AsB + 2 * 16384, BsB + 2 * 16384, 0, 0, "0");
    GROUP4(AsB + 3 * 16384, BsB + 3 * 16384, 0, 0, "0");

    // epilogue: y = acc * inv_sx[row] * inv_sw + bias[col]
    const float invsw = params[1];
    const int rl = (lane >> 4) * 4;
#pragma unroll
    for (int i = 0; i < 8; ++i) {
        const int grow_base = (int)arow0 + wr * 128 + i * 16 + rl;
        float isx[4];
#pragma unroll
        for (int r = 0; r < 4; ++r) isx[r] = inv_sx[grow_base + r] * invsw;
#pragma unroll
        for (int j = 0; j < 4; ++j) {
            const int gcol = (int)brow0 + wc * 64 + j * 16 + lrow;
            const float bb = bias[gcol];
#pragma unroll
            for (int r = 0; r < 4; ++r) {
                y[(size_t)(grow_base + r) * N_COLS + gcol] =
                    (float)acc[i][j][r] * isx[r] + bb;
            }
        }
    }
#undef GLD
#undef RDA4
#undef RDB2
#undef MFMA8
#undef BARR
#undef LGKM0
#undef GROUP4
}

// ---------------- launch ----------------
extern "C" void kernel_launch(void* const* d_in, const int* in_sizes, int n_in,
                              void* d_out, int out_size, void* d_ws, size_t ws_size,
                              hipStream_t stream) {
    const float* x    = (const float*)d_in[0];
    const float* wt   = (const float*)d_in[1];
    const float* bias = (const float*)d_in[2];
    float* y = (float*)d_out;

    if (ws_size < WS_NEED) return;

    char* ws = (char*)d_ws;
    float* partials = (float*)(ws + WS_PARTIALS);
    float* params   = (float*)(ws + WS_PARAMS);
    float* inv_sx   = (float*)(ws + WS_INVSX);
    int8_t* qx = (int8_t*)(ws + WS_QX);
    int8_t* qw = (int8_t*)(ws + WS_QW);

    hipLaunchKernelGGL(act_quant_kernel,   dim3(8192), dim3(256), 0, stream, x, qx, inv_sx);
    hipLaunchKernelGGL(wabs_partial_kernel,dim3(2048), dim3(256), 0, stream, wt, partials);
    hipLaunchKernelGGL(wfinal_kernel,      dim3(1),    dim3(256), 0, stream, partials, params);
    hipLaunchKernelGGL(w_quant_kernel,     dim3(4096), dim3(256), 0, stream, wt, qw, params);
    hipLaunchKernelGGL(gemm_i8_kernel,     dim3(2048), dim3(512), 0, stream,
                       qx, qw, inv_sx, params, bias, y);
}

// Round 4
// 761.680 us; speedup vs baseline: 1.2408x; 1.0620x over previous
//
#include <hip/hip_runtime.h>
#include <stdint.h>

// BitNet b1.58 column-parallel linear:
//   y[m,n] = (sum_k qx[m,k]*qw[n,k]) * inv_sx[m] * inv_sw + bias[n]
// M=8192 (B*S), N=16384 (D_OUT), K=4096 (D_IN)

#define M_ROWS 8192
#define N_COLS 16384
#define K_DIM  4096
#define NT     (K_DIM / 64)   // 64 K-steps of 64 bytes

typedef int v4i __attribute__((ext_vector_type(4)));

// ---------------- workspace layout ----------------
#define WS_PARTIALS 0
#define WS_PARAMS   8192
#define WS_INVSX    8448
#define WS_QX       41216
#define WS_QW       (41216 + 33554432)
#define WS_NEED     ((size_t)WS_QW + 67108864)

// ---------------- activation quant: per-row int8 absmax ----------------
__device__ __forceinline__ int quant_act1(float v, float s) {
    float q = rintf(v * s);               // round-half-even, matches jnp.round
    q = fminf(127.0f, fmaxf(-128.0f, q));
    return (int)q;
}

__global__ __launch_bounds__(256) void act_quant_kernel(const float* __restrict__ x,
                                                        int8_t* __restrict__ qx,
                                                        float* __restrict__ inv_sx) {
    const int row = blockIdx.x;
    const int t = threadIdx.x;
    const float4* xr = (const float4*)(x + (size_t)row * K_DIM);

    float4 v[4];
    float m = 0.0f;
#pragma unroll
    for (int i = 0; i < 4; ++i) {
        v[i] = xr[t + 256 * i];
        m = fmaxf(m, fmaxf(fmaxf(fabsf(v[i].x), fabsf(v[i].y)),
                           fmaxf(fabsf(v[i].z), fabsf(v[i].w))));
    }
#pragma unroll
    for (int off = 32; off > 0; off >>= 1) m = fmaxf(m, __shfl_xor(m, off));
    __shared__ float wm[4];
    if ((t & 63) == 0) wm[t >> 6] = m;
    __syncthreads();
    m = fmaxf(fmaxf(wm[0], wm[1]), fmaxf(wm[2], wm[3]));
    m = fmaxf(m, 1e-5f);                  // clip(max, EPS)
    const float scale = 127.0f / m;
    if (t == 0) inv_sx[row] = 1.0f / scale;

    int* qr = (int*)(qx + (size_t)row * K_DIM);
#pragma unroll
    for (int i = 0; i < 4; ++i) {
        int b0 = quant_act1(v[i].x, scale) & 255;
        int b1 = quant_act1(v[i].y, scale) & 255;
        int b2 = quant_act1(v[i].z, scale) & 255;
        int b3 = quant_act1(v[i].w, scale) & 255;
        qr[t + 256 * i] = b0 | (b1 << 8) | (b2 << 16) | (b3 << 24);
    }
}

// ---------------- weight abs-sum (deterministic two-stage) ----------------
__global__ __launch_bounds__(256) void wabs_partial_kernel(const float* __restrict__ w,
                                                           float* __restrict__ partials) {
    const int t = threadIdx.x;
    const size_t base = (size_t)blockIdx.x * 8192;   // float4 units
    const float4* w4 = (const float4*)w;
    float s = 0.0f;
#pragma unroll 8
    for (int i = 0; i < 32; ++i) {
        float4 v = w4[base + (size_t)i * 256 + t];
        s += fabsf(v.x) + fabsf(v.y) + fabsf(v.z) + fabsf(v.w);
    }
#pragma unroll
    for (int off = 32; off > 0; off >>= 1) s += __shfl_xor(s, off);
    __shared__ float wp[4];
    if ((t & 63) == 0) wp[t >> 6] = s;
    __syncthreads();
    if (t == 0) partials[blockIdx.x] = (wp[0] + wp[1]) + (wp[2] + wp[3]);
}

__global__ __launch_bounds__(256) void wfinal_kernel(const float* __restrict__ partials,
                                                     float* __restrict__ params) {
    __shared__ double sh[256];
    const int t = threadIdx.x;
    double s = 0.0;
    for (int i = t; i < 2048; i += 256) s += (double)partials[i];
    sh[t] = s;
    __syncthreads();
    for (int off = 128; off > 0; off >>= 1) {
        if (t < off) sh[t] += sh[t + off];
        __syncthreads();
    }
    if (t == 0) {
        float mean = (float)(sh[0] / 67108864.0);
        mean = fmaxf(mean, 1e-5f);        // clip(mean, EPS)
        float scale = 1.0f / mean;        // scale_w
        params[0] = scale;
        params[1] = 1.0f / scale;         // inv_sw
    }
}

// ---------------- weight quant: per-tensor ternary ----------------
__device__ __forceinline__ int quant_w1(float v, float s) {
    float q = rintf(v * s);
    q = fminf(1.0f, fmaxf(-1.0f, q));
    return (int)q;
}

__global__ __launch_bounds__(256) void w_quant_kernel(const float* __restrict__ w,
                                                      int8_t* __restrict__ qw,
                                                      const float* __restrict__ params) {
    const float scale = params[0];
    const int stride = gridDim.x * 256;
    const float4* w4 = (const float4*)w;
    int* q4 = (int*)qw;
    for (int g = blockIdx.x * 256 + threadIdx.x; g < 16777216; g += stride) {
        float4 v = w4[g];
        int b0 = quant_w1(v.x, scale) & 255;
        int b1 = quant_w1(v.y, scale) & 255;
        int b2 = quant_w1(v.z, scale) & 255;
        int b3 = quant_w1(v.w, scale) & 255;
        q4[g] = b0 | (b1 << 8) | (b2 << 16) | (b3 << 24);
    }
}

// ---------------- int8 GEMM: 256x256, 4 phases x 16-MFMA, reg-pipelined counted lgkm ----
// 8 waves (2M x 4N), per-wave 128x64 output, mfma_i32_16x16x64_i8.
// Iter = 2 K-steps (64B each, slot = ks&3, 4-slot ring). Per phase:
//   { ds_read NEXT phase's frags (reg dbuf aP/aQ, bP/bQ) | GLDs |
//     s_waitcnt lgkmcnt(N_issued) -> THIS phase's frags ready |
//     setprio(1) 16xMFMA setprio(0) | [vmcnt(4) publish] | s_barrier }
// LDS reads execute under the MFMA cluster (counted lgkm, not drain-0).
// Staging: GLD4(t0+2)@P0, GLD4(t0+3)@P1. vmcnt(4)@P0 proves t0+1 (read P1);
// vmcnt(4)@P2 proves t0+2 (read P3). Never vmcnt(0) in the main loop.
// 16B-chunk XOR swizzle on both global source and ds_read address (verified: 0 conflicts).
__global__ __launch_bounds__(512, 2) void gemm_i8_kernel(const int8_t* __restrict__ qx,
                                                         const int8_t* __restrict__ qw,
                                                         const float* __restrict__ inv_sx,
                                                         const float* __restrict__ params,
                                                         const float* __restrict__ bias,
                                                         float* __restrict__ y) {
    __shared__ __align__(16) int8_t As[4][16384];
    __shared__ __align__(16) int8_t Bs[4][16384];
    int8_t* AsB = &As[0][0];
    int8_t* BsB = &Bs[0][0];

    const int tid = threadIdx.x;
    const int lane = tid & 63;
    const int w = tid >> 6;           // wave 0..7
    const int wr = w >> 2;            // 0..1  (M half)
    const int wc = w & 3;             // 0..3  (N quarter)
    const int wbase = w * 1024;       // wave-uniform LDS staging base (64 lanes x 16B)

    // XCD-aware bijective swizzle: 2048 blocks, 8 XCDs
    const int bid = blockIdx.x;
    const int swz = (bid & 7) * 256 + (bid >> 3);
    const int bn = swz & 63;          // 64 n-blocks
    const int bm = swz >> 6;          // 32 m-blocks

    const size_t arow0 = (size_t)bm * 256;
    const size_t brow0 = (size_t)bn * 256;

    // staging addressing: 512 chunks of 16B per 128-row half; thread tid -> chunk tid
    const int r0 = tid >> 2;                       // row 0..127 within half
    const int kc0 = (tid & 3) ^ ((r0 >> 1) & 3);   // swizzled k-slot (involution)
    const int8_t* gA0 = qx + (arow0 + r0) * K_DIM + kc0 * 16;
    const int8_t* gA1 = gA0 + (size_t)128 * K_DIM;
    const int8_t* gB0 = qw + (brow0 + r0) * K_DIM + kc0 * 16;
    const int8_t* gB1 = gB0 + (size_t)128 * K_DIM;

#define GLD(g, l)                                                                        \
    __builtin_amdgcn_global_load_lds((const __attribute__((address_space(1))) void*)(g), \
                                     (__attribute__((address_space(3))) void*)(l), 16, 0, 0)

#define GLD4(ks)                                                                         \
    do {                                                                                 \
        const int _s = (ks) & 3;                                                         \
        const size_t _o = (size_t)(ks) * 64;                                             \
        GLD(gA0 + _o, AsB + _s * 16384 + wbase);                                         \
        GLD(gA1 + _o, AsB + _s * 16384 + 8192 + wbase);                                  \
        GLD(gB0 + _o, BsB + _s * 16384 + wbase);                                         \
        GLD(gB1 + _o, BsB + _s * 16384 + 8192 + wbase);                                  \
    } while (0)

    // fragment ds_read offsets (within one 16KB slot)
    const int ksub = lane >> 4;       // 16B k-chunk 0..3
    const int lrow = lane & 15;
    int aoff[8], boff[4];
#pragma unroll
    for (int i = 0; i < 8; ++i) {
        int ra = wr * 128 + i * 16 + lrow;
        aoff[i] = ra * 64 + ((ksub ^ ((ra >> 1) & 3)) << 4);
    }
#pragma unroll
    for (int j = 0; j < 4; ++j) {
        int rb = wc * 64 + j * 16 + lrow;
        boff[j] = rb * 64 + ((ksub ^ ((rb >> 1) & 3)) << 4);
    }

    v4i acc[8][4];
#pragma unroll
    for (int i = 0; i < 8; ++i)
#pragma unroll
        for (int j = 0; j < 4; ++j) acc[i][j] = (v4i){0, 0, 0, 0};

    // register double-buffered fragment sets
    v4i aP[4], aQ[4], bP[4], bQ[4];

#define RDA(dst, base_, lo)                                                    \
    do {                                                                       \
        _Pragma("unroll") for (int _k = 0; _k < 4; ++_k)                       \
            dst[_k] = *(const v4i*)((base_) + aoff[(lo) + _k]);                \
    } while (0)
#define RDB(dst, base_)                                                        \
    do {                                                                       \
        _Pragma("unroll") for (int _k = 0; _k < 4; ++_k)                       \
            dst[_k] = *(const v4i*)((base_) + boff[_k]);                       \
    } while (0)

#define MF16(A_, B_, ILO)                                                      \
    do {                                                                       \
        __builtin_amdgcn_s_setprio(1);                                         \
        _Pragma("unroll") for (int _i = 0; _i < 4; ++_i)                       \
            _Pragma("unroll") for (int _j = 0; _j < 4; ++_j)                   \
                acc[(ILO) + _i][_j] = __builtin_amdgcn_mfma_i32_16x16x64_i8(   \
                    A_[_i], B_[_j], acc[(ILO) + _i][_j], 0, 0, 0);             \
        __builtin_amdgcn_s_setprio(0);                                         \
    } while (0)

// counted lgkm: waits for PREVIOUS phase's ds_reads (this phase's N stay outstanding)
#define WAITL(NSTR)                                                            \
    do {                                                                       \
        __builtin_amdgcn_sched_barrier(0);                                     \
        asm volatile("s_waitcnt lgkmcnt(" NSTR ")" ::: "memory");              \
        __builtin_amdgcn_sched_barrier(0);                                     \
    } while (0)
#define VM4() asm volatile("s_waitcnt vmcnt(4)" ::: "memory")
#define VM0() asm volatile("s_waitcnt vmcnt(0)" ::: "memory")
#define BARR()                                                                 \
    do {                                                                       \
        __builtin_amdgcn_s_barrier();                                          \
        __builtin_amdgcn_sched_barrier(0);                                     \
    } while (0)

    // prologue: stage K-steps 0,1; publish slot 0; preload frags for P0
    GLD4(0);
    GLD4(1);
    asm volatile("s_waitcnt vmcnt(4)" ::: "memory");   // K-step 0 landed
    BARR();
    RDA(aP, AsB, 0);
    RDB(bP, BsB);

#pragma unroll 1
    for (int i = 0; i < 31; ++i) {
        const int t0 = 2 * i;
        const int8_t* pa0 = AsB + (t0 & 3) * 16384;
        const int8_t* pb1 = BsB + ((t0 + 1) & 3) * 16384;
        const int8_t* pa1 = AsB + ((t0 + 1) & 3) * 16384;
        const int8_t* pa2 = AsB + ((t0 + 2) & 3) * 16384;
        const int8_t* pb2 = BsB + ((t0 + 2) & 3) * 16384;

        // P0: prefetch a-hi(s0); stage t0+2; MFMA lo(s0)
        RDA(aQ, pa0, 4);
        GLD4(t0 + 2);
        WAITL("4");
        MF16(aP, bP, 0);
        VM4();                 // proves t0+1 landed (only t0+2's 4 remain)
        BARR();                // publish slot t0+1

        // P1: prefetch lo+b(s1); stage t0+3; MFMA hi(s0)
        RDA(aP, pa1, 0);
        RDB(bQ, pb1);
        GLD4(t0 + 3);
        WAITL("8");
        MF16(aQ, bP, 4);
        BARR();

        // P2: prefetch a-hi(s1); MFMA lo(s1)
        RDA(aQ, pa1, 4);
        WAITL("4");
        MF16(aP, bQ, 0);
        VM4();                 // proves t0+2 landed (only t0+3's 4 remain)
        BARR();                // publish slot t0+2

        // P3: prefetch lo+b(s0' = slot t0+2); MFMA hi(s1)
        RDA(aP, pa2, 0);
        RDB(bP, pb2);
        WAITL("8");
        MF16(aQ, bQ, 4);
        BARR();
    }

    // epilogue: K-steps 62 (slot 2), 63 (slot 3); aP,bP hold lo+b of slot 62
    {
        const int8_t* pa62 = AsB + 2 * 16384;
        const int8_t* pa63 = AsB + 3 * 16384;
        const int8_t* pb63 = BsB + 3 * 16384;
        // E0
        RDA(aQ, pa62, 4);
        WAITL("4");
        MF16(aP, bP, 0);
        VM0();                 // K-step 63 landed
        BARR();                // publish slot 63
        // E1
        RDA(aP, pa63, 0);
        RDB(bQ, pb63);
        WAITL("8");
        MF16(aQ, bP, 4);
        // E2
        RDA(aQ, pa63, 4);
        WAITL("4");
        MF16(aP, bQ, 0);
        // E3
        WAITL("0");
        MF16(aQ, bQ, 4);
    }

    // epilogue: y = acc * inv_sx[row] * inv_sw + bias[col]
    const float invsw = params[1];
    const int rl = (lane >> 4) * 4;
#pragma unroll
    for (int i = 0; i < 8; ++i) {
        const int grow_base = (int)arow0 + wr * 128 + i * 16 + rl;
        float isx[4];
#pragma unroll
        for (int r = 0; r < 4; ++r) isx[r] = inv_sx[grow_base + r] * invsw;
#pragma unroll
        for (int j = 0; j < 4; ++j) {
            const int gcol = (int)brow0 + wc * 64 + j * 16 + lrow;
            const float bb = bias[gcol];
#pragma unroll
            for (int r = 0; r < 4; ++r) {
                y[(size_t)(grow_base + r) * N_COLS + gcol] =
                    (float)acc[i][j][r] * isx[r] + bb;
            }
        }
    }
#undef GLD
#undef GLD4
#undef RDA
#undef RDB
#undef MF16
#undef WAITL
#undef VM4
#undef VM0
#undef BARR
}

// ---------------- launch ----------------
extern "C" void kernel_launch(void* const* d_in, const int* in_sizes, int n_in,
                              void* d_out, int out_size, void* d_ws, size_t ws_size,
                              hipStream_t stream) {
    const float* x    = (const float*)d_in[0];
    const float* wt   = (const float*)d_in[1];
    const float* bias = (const float*)d_in[2];
    float* y = (float*)d_out;

    if (ws_size < WS_NEED) return;

    char* ws = (char*)d_ws;
    float* partials = (float*)(ws + WS_PARTIALS);
    float* params   = (float*)(ws + WS_PARAMS);
    float* inv_sx   = (float*)(ws + WS_INVSX);
    int8_t* qx = (int8_t*)(ws + WS_QX);
    int8_t* qw = (int8_t*)(ws + WS_QW);

    hipLaunchKernelGGL(act_quant_kernel,   dim3(8192), dim3(256), 0, stream, x, qx, inv_sx);
    hipLaunchKernelGGL(wabs_partial_kernel,dim3(2048), dim3(256), 0, stream, wt, partials);
    hipLaunchKernelGGL(wfinal_kernel,      dim3(1),    dim3(256), 0, stream, partials, params);
    hipLaunchKernelGGL(w_quant_kernel,     dim3(4096), dim3(256), 0, stream, wt, qw, params);
    hipLaunchKernelGGL(gemm_i8_kernel,     dim3(2048), dim3(512), 0, stream,
                       qx, qw, inv_sx, params, bias, y);
}